// Round 17
// baseline (168.599 us; speedup 1.0000x reference)
//
#include <hip/hip_runtime.h>
#include <hip/hip_bf16.h>

#define DEV __device__ __forceinline__

typedef __attribute__((ext_vector_type(8))) short bf16x8;
typedef __attribute__((ext_vector_type(4))) float f32x4;

// N=65536 tokens, 8 heads, head dim 32, feature dim 256, block 256
static constexpr float QSCALE = 0.17677669529663687f; // 1/sqrt(32)
static constexpr float LOG2E  = 1.4426950408889634f;

DEV unsigned short f2bf(float f) {
    union { float f; unsigned int u; } a; a.f = f;
    unsigned int r = (a.u + 0x7fffu + ((a.u >> 16) & 1u)) >> 16; // RNE
    return (unsigned short)r;
}
DEV unsigned int pack2bf(float lo, float hi) {   // v_cvt_pk_bf16_f32 on gfx950
    float2 t; t.x = lo; t.y = hi;
    __hip_bfloat162 h = __float22bfloat162_rn(t);
    unsigned int u; __builtin_memcpy(&u, &h, 4);
    return u;
}
DEV unsigned short f2bf1(float f) {              // 1 VALU (cvt_pk, keep low half)
    return (unsigned short)(pack2bf(f, 0.f) & 0xffffu);
}

// ---------------- pre-chain, 2 dispatches ----------------
// K1: block-local counting sort + keyarr + small-weight prep + per-head fused
// matrices M_h = s*wq_h^T@wk_h and G_h[f][o] = sum_d wv[h32+d][f]*wout[o][h32+d].
__global__ __launch_bounds__(256) void kprep(
    const float* __restrict__ coords,
    const float* __restrict__ wq, const float* __restrict__ wk,
    const float* __restrict__ wv, const float* __restrict__ w_out,
    const float* __restrict__ ff1, const float* __restrict__ ff2,
    const float* __restrict__ w_rpe,
    unsigned int* __restrict__ hseg,        // [256 kblocks][256 buckets] packed
    unsigned int* __restrict__ locmemb,     // [256 kblocks][256] bucket-grouped ids
    unsigned int* __restrict__ keyarr,      // [65536] float bits of coords[:,0]
    unsigned short* ff1b, unsigned short* ff2b,
    unsigned short* mhb, unsigned short* ghb, float* w2)
{
    __shared__ unsigned int lhist[256];
    __shared__ unsigned int s[256];
    __shared__ unsigned int loff[256];
    __shared__ float part[4];
    int tid = threadIdx.x;
    int g = blockIdx.x * 256 + tid;

    lhist[tid] = 0u;
    float v = coords[(size_t)g * 3];
    keyarr[g] = __float_as_uint(v);          // keys >= 0 -> bit compare works
    int b8 = (int)(v * 256.0f);
    b8 = b8 < 0 ? 0 : (b8 > 255 ? 255 : b8);
    __syncthreads();
    unsigned int myl = atomicAdd(&lhist[b8], 1u);

    // FFN weight conversion (blocks 0..7)
    if (g < 1024)            ff1b[g] = f2bf(ff1[g]);
    else if (g < 2048)       ff2b[g - 1024] = f2bf(ff2[g - 1024]);

    // fused per-head matrices (blocks 64..79): p = (h<<1)|m
    if (blockIdx.x >= 64 && blockIdx.x < 80) {
        int pp = blockIdx.x - 64;
        int m = pp & 1, h = pp >> 1;
#pragma unroll 1
        for (int k = 0; k < 4; k++) {
            int e = k * 256 + tid;
            int gg = e >> 5, f = e & 31;     // gg = output col (g of T / o), f = k-dim
            float acc = 0.f;
            if (m == 0) {
#pragma unroll 4
                for (int d = 0; d < 32; d++)
                    acc += wq[(h * 32 + d) * 32 + f] * wk[(h * 32 + d) * 32 + gg];
                mhb[h * 1024 + gg * 32 + f] = f2bf(acc * (QSCALE * LOG2E));
            } else {
#pragma unroll 4
                for (int d = 0; d < 32; d++)
                    acc += wv[(h * 32 + d) * 32 + f] * w_out[gg * 256 + h * 32 + d];
                ghb[h * 1024 + gg * 32 + f] = f2bf(acc);
            }
        }
    }

    if (blockIdx.x >= 240) {                 // 16 blocks: w2[p], p = h*2 + c
        int p = blockIdx.x - 240;
        int h = p >> 1, c = p & 1;
        int d = tid >> 3, j = tid & 7;
        float w = w_rpe[(h * 32 + d) * 16 + c * 8 + j];
        float w2v = w * w;
        for (int m = 32; m >= 1; m >>= 1) w2v += __shfl_xor(w2v, m);
        if ((tid & 63) == 0) part[tid >> 6] = w2v;
        __syncthreads();
        if (tid == 0) w2[p] = (part[0] + part[1] + part[2] + part[3]) * (1.0f / 256.0f) * LOG2E;
    }
    __syncthreads();

    unsigned int cnt = lhist[tid];
    s[tid] = cnt; __syncthreads();
    for (int off = 1; off < 256; off <<= 1) {
        unsigned int t = (tid >= off) ? s[tid - off] : 0u;
        __syncthreads();
        s[tid] += t;
        __syncthreads();
    }
    unsigned int lexcl = s[tid] - cnt;
    loff[tid] = lexcl;
    hseg[blockIdx.x * 256 + tid] = (lexcl << 16) | cnt;   // coalesced, packed
    __syncthreads();

    locmemb[blockIdx.x * 256 + loff[b8] + myl] = (unsigned int)g;
}

// K2: one block per bucket, 512 threads (unchanged)
__global__ __launch_bounds__(512) void kbucket(
    const unsigned int* __restrict__ hseg,
    const unsigned int* __restrict__ locmemb,
    const unsigned int* __restrict__ keyarr,
    unsigned int* __restrict__ order)
{
    __shared__ unsigned int s[256];
    __shared__ unsigned int csum[512];
    __shared__ unsigned int mkey[512];
    __shared__ unsigned int midx[512];
    int tid = threadIdx.x;
    int b = blockIdx.x;
    int t8 = tid & 255, hi = tid >> 8;

    unsigned int tot = 0;
#pragma unroll 16
    for (int k = 0; k < 128; k++) tot += hseg[(hi * 128 + k) * 256 + t8] & 0xffffu;
    csum[tid] = tot;
    __syncthreads();
    if (tid < 256) s[tid] = csum[tid] + csum[tid + 256];
    __syncthreads();

    for (int off = 1; off < 256; off <<= 1) {
        unsigned int t = 0;
        if (tid < 256 && tid >= off) t = s[tid - off];
        __syncthreads();
        if (tid < 256) s[tid] += t;
        __syncthreads();
    }
    unsigned int start = (b == 0) ? 0u : s[b - 1];
    __syncthreads();

    unsigned int segcnt = 0, segoff = 0;
    if (tid < 256) {
        unsigned int pk = hseg[tid * 256 + b];
        segcnt = pk & 0xffffu;
        segoff = pk >> 16;
    }
    __syncthreads();
    if (tid < 256) s[tid] = segcnt;
    __syncthreads();
    for (int off = 1; off < 256; off <<= 1) {
        unsigned int t = 0;
        if (tid < 256 && tid >= off) t = s[tid - off];
        __syncthreads();
        if (tid < 256) s[tid] += t;
        __syncthreads();
    }
    unsigned int dst = (tid < 256) ? s[tid] - segcnt : 0u;
    unsigned int cntb = s[255];
    if (cntb > 512u) cntb = 512u;
    __syncthreads();

    if (tid < 256) {
        for (unsigned int j = 0; j < segcnt; j++) {
            unsigned int p = dst + j;
            if (p < 512u) midx[p] = locmemb[tid * 256 + segoff + j];
        }
    }
    __syncthreads();
    for (unsigned int p = tid; p < cntb; p += 512) mkey[p] = keyarr[midx[p]];
    __syncthreads();

    for (unsigned int m = tid; m < cntb; m += 512) {
        unsigned int km = mkey[m], im = midx[m];
        unsigned int r = 0;
        for (unsigned int j = 0; j < cntb; j++) {
            unsigned int kj = mkey[j];
            r += (kj < km || (kj == km && midx[j] < im)) ? 1u : 0u;
        }
        order[start + r] = im;
    }
}

// ---------------- fused attention, Q/K/V-free (R15 core, uniform dual-quarter) -----
// R17 = R16 resubmitted (R16 bench was an infrastructure failure -- "container
// failed twice" -- no kernel evidence). One change vs R15 (launch mapping only):
// eliminate the phase imbalance. R15's grid 768 ran 3 blocks/CU until the 512
// single-quarter blocks retired, then the 256 dual blocks finished alone at
// 1 block/CU (4 waves) -- the back half of the dispatch was starved. New grid
// 512: EVERY block is dual-quarter (q0 = bh>>8 in {0,1}; quarters q0 and q0+2
// of bucket bh&255). Uniform work -> 2 blocks/CU (8 waves) constant, no starved
// tail; stage A runs 512x (fewer duplicated gathers). Pair shares bh&7 -> XCD.
// Head-loop body byte-identical; FETCH is the spill tripwire.
// LDS: xn 16384 + xnT 16896 + kext 2048 + pf 2048 + Pst 9216 = 46592.
__global__ __launch_bounds__(256, 3) void kattn(
    const float* __restrict__ x, const float* __restrict__ g1, const float* __restrict__ be1,
    const unsigned int* __restrict__ order, const float* __restrict__ coords,
    const float* __restrict__ w2,
    const unsigned short* __restrict__ mhb, const unsigned short* __restrict__ ghb,
    const float* __restrict__ b_out,
    const float* __restrict__ g2, const float* __restrict__ be2,
    const unsigned short* __restrict__ ff1b, const float* __restrict__ ffb1,
    const unsigned short* __restrict__ ff2b, const float* __restrict__ ffb2,
    float* __restrict__ out)
{
    __shared__ unsigned short xn[256][32];       // 16384 B  LN'd x, chunk-swizzled
    __shared__ unsigned short xnT[32][264];      // 16896 B  [feature][jinv(token)]
    __shared__ unsigned short kext[256][4];      //  2048 B  {a, b, a^2, b^2} bf16
    __shared__ float2 pf[256];                   //  2048 B  f32 coords
    __shared__ unsigned short Pst[4][16][72];    //  9216 B  wave-private staging

    int bh = blockIdx.x;
    int p = bh & 255;
    int b = (p & 7) * 32 + (p >> 3);            // bucket; pair shares bh&7 (XCD)
    int q0 = bh >> 8;                           // first quarter (0 or 1)
    int tid = threadIdx.x, wave = tid >> 6, lane = tid & 63;
    int col = lane & 15, quad = lane >> 4;

    // ---- stage A: gather x row, LN1 -> xn (swizzled) + xnT (permuted transpose) ----
    {
        int t = tid;
        int tok = (int)order[b * 256 + t];
        float a = coords[tok * 3 + 1], bb = coords[tok * 3 + 2];
        pf[t] = make_float2(a, bb);
        uint2 kv;
        kv.x = pack2bf(a, bb);
        kv.y = pack2bf(a * a, bb * bb);
        *(uint2*)&kext[t][0] = kv;

        float xv[32];
        const float4* xr = (const float4*)(x + (size_t)tok * 32);
#pragma unroll
        for (int q4 = 0; q4 < 8; q4++) {
            float4 v4 = xr[q4];
            xv[q4 * 4 + 0] = v4.x; xv[q4 * 4 + 1] = v4.y; xv[q4 * 4 + 2] = v4.z; xv[q4 * 4 + 3] = v4.w;
        }
        float mu = 0.f;
#pragma unroll
        for (int d = 0; d < 32; d++) mu += xv[d];
        mu *= (1.0f / 32.0f);
        float var = 0.f;
#pragma unroll
        for (int d = 0; d < 32; d++) { float c = xv[d] - mu; var += c * c; }
        var *= (1.0f / 32.0f);
        float rstd = rsqrtf(var + 1e-5f);
        unsigned int pk[16];
#pragma unroll
        for (int w = 0; w < 16; w++) {
            float a2 = (xv[2 * w] - mu) * rstd * g1[2 * w] + be1[2 * w];
            float b2 = (xv[2 * w + 1] - mu) * rstd * g1[2 * w + 1] + be1[2 * w + 1];
            pk[w] = pack2bf(a2, b2);
        }
        int v = (t >> 1) & 3;                    // chunk swizzle key
        uint4* dst = (uint4*)&xn[t][0];
#pragma unroll
        for (int w4 = 0; w4 < 4; w4++) {
            uint4 v4; v4.x = pk[w4*4]; v4.y = pk[w4*4+1]; v4.z = pk[w4*4+2]; v4.w = pk[w4*4+3];
            dst[w4 ^ v] = v4;                    // logical chunk w4 -> physical w4^v
        }
        int jv = (t & ~63) + (t & 15) * 4 + ((t >> 4) & 3);   // jinv permutation
#pragma unroll
        for (int f = 0; f < 16; f++) {
            xnT[2 * f][jv]     = (unsigned short)(pk[f] & 0xffffu);
            xnT[2 * f + 1][jv] = (unsigned short)(pk[f] >> 16);
        }
    }
    __syncthreads();                             // stage A visibility (required)

    int kswz = (quad ^ ((col >> 1) & 3)) * 8;    // B-read swizzle (row = nt*16+col)
    const f32x4 zz = { 0.f, 0.f, 0.f, 0.f };

#pragma unroll 1
    for (int qi = 0; qi < 2; qi++) {
        int qbase = (q0 + qi * 2) * 64;          // quarters q0 and q0+2
        // per-quarter hoists
        int srow = qbase + wave * 16;            // strip base (16 q-rows per wave)
        int myrow = srow + col;                  // A-row of this lane
        bf16x8 qa_x = *(const bf16x8*)&xn[myrow][(quad ^ ((myrow >> 1) & 3)) * 8];
        float2 pm = pf[myrow];

        f32x4 aggr0 = { 0.f, 0.f, 0.f, 0.f }, aggr1 = { 0.f, 0.f, 0.f, 0.f };

#pragma unroll 1
        for (int h = 0; h < 8; h++) {
            __builtin_amdgcn_sched_barrier(0);   // compile-time anchor only; waves drift

            // per-head score matrix fragments (global 16 B loads, L2-resident)
            bf16x8 m0 = *(const bf16x8*)(mhb + (size_t)h * 1024 + (size_t)col * 32 + quad * 8);
            bf16x8 m1 = *(const bf16x8*)(mhb + (size_t)h * 1024 + (size_t)(16 + col) * 32 + quad * 8);
            float w0 = w2[2 * h], w1 = w2[2 * h + 1];   // already * log2e
            unsigned int qp0 = quad == 0 ? pack2bf(2.0f * w0 * pm.x, 2.0f * w1 * pm.y) : 0u;
            unsigned int qp1 = quad == 0 ? pack2bf(-w0, -w1) : 0u;
            bf16x8 qe;
            qe[0] = (short)(qp0 & 0xffffu); qe[1] = (short)(qp0 >> 16);
            qe[2] = (short)(qp1 & 0xffffu); qe[3] = (short)(qp1 >> 16);
            qe[4] = 0; qe[5] = 0; qe[6] = 0; qe[7] = 0;

            // T = xns @ M_h (C: col=g-col, row=quad*4+r) -> LDS transpose -> A-frag
            f32x4 t0 = __builtin_amdgcn_mfma_f32_16x16x32_bf16(qa_x, m0, zz, 0, 0, 0);
            f32x4 t1 = __builtin_amdgcn_mfma_f32_16x16x32_bf16(qa_x, m1, zz, 0, 0, 0);
#pragma unroll
            for (int r = 0; r < 4; r++) {
                int ii = quad * 4 + r, sw = (ii >> 1) & 3;
                int ga = col, gb = 16 + col;
                Pst[wave][ii][((ga >> 3) ^ sw) * 8 + (ga & 7)] = f2bf1(t0[r]);
                Pst[wave][ii][((gb >> 3) ^ sw) * 8 + (gb & 7)] = f2bf1(t1[r]);
            }
            bf16x8 ta = *(const bf16x8*)&Pst[wave][col][(quad ^ ((col >> 1) & 3)) * 8];

            // S = T @ xn^T + bias, processed in TWO halves of 8 key-tiles so the
            // accumulator live range peaks at 32 VGPRs (R8's 64 spilled to scratch).
            float rsum[4] = { 0.f, 0.f, 0.f, 0.f };
            f32x4 o0 = zz, o1 = zz;
#pragma unroll 1
            for (int half = 0; half < 2; half++) {
                f32x4 acc8[8];
#pragma unroll
                for (int nt8 = 0; nt8 < 8; nt8++) {
                    int nt = half * 8 + nt8;
                    bf16x8 kb = *(const bf16x8*)&xn[nt * 16 + col][kswz];
                    uint2 kv = *(const uint2*)&kext[nt * 16 + col][0];
                    unsigned int ea0 = quad == 0 ? kv.x : 0u;
                    unsigned int ea1 = quad == 0 ? kv.y : 0u;
                    bf16x8 ke;
                    ke[0] = (short)(ea0 & 0xffffu); ke[1] = (short)(ea0 >> 16);
                    ke[2] = (short)(ea1 & 0xffffu); ke[3] = (short)(ea1 >> 16);
                    ke[4] = 0; ke[5] = 0; ke[6] = 0; ke[7] = 0;
                    f32x4 z = __builtin_amdgcn_mfma_f32_16x16x32_bf16(ta, kb, zz, 0, 0, 0);
                    acc8[nt8] = __builtin_amdgcn_mfma_f32_16x16x32_bf16(qe, ke, z, 0, 0, 0);
                }
#pragma unroll
                for (int cc = 0; cc < 2; cc++) {
                    int c = half * 2 + cc;
#pragma unroll
                    for (int r = 0; r < 4; r++) {
                        float e0 = __builtin_amdgcn_exp2f(acc8[cc * 4 + 0][r]);
                        float e1 = __builtin_amdgcn_exp2f(acc8[cc * 4 + 1][r]);
                        float e2 = __builtin_amdgcn_exp2f(acc8[cc * 4 + 2][r]);
                        float e3 = __builtin_amdgcn_exp2f(acc8[cc * 4 + 3][r]);
                        rsum[r] += (e0 + e1) + (e2 + e3);
                        uint2 pk;
                        pk.x = pack2bf(e0, e1);
                        pk.y = pack2bf(e2, e3);
                        *(uint2*)&Pst[wave][quad * 4 + r][col * 4] = pk;  // kloc = col*4+t
                    }
#pragma unroll
                    for (int k2 = 0; k2 < 2; k2++) {
                        bf16x8 pa = *(const bf16x8*)&Pst[wave][col][k2 * 32 + quad * 8];
                        bf16x8 b0 = *(const bf16x8*)&xnT[col][c * 64 + k2 * 32 + quad * 8];
                        bf16x8 b1 = *(const bf16x8*)&xnT[16 + col][c * 64 + k2 * 32 + quad * 8];
                        o0 = __builtin_amdgcn_mfma_f32_16x16x32_bf16(pa, b0, o0, 0, 0, 0);
                        o1 = __builtin_amdgcn_mfma_f32_16x16x32_bf16(pa, b1, o1, 0, 0, 0);
                    }
                }
            }

            // scale by 1/sum, stage PXs, fused out-proj accumulate via G_h (loaded late)
#pragma unroll
            for (int r = 0; r < 4; r++) {
                float su = rsum[r];
                su += __shfl_xor(su, 1); su += __shfl_xor(su, 2);
                su += __shfl_xor(su, 4); su += __shfl_xor(su, 8);
                float rl = __builtin_amdgcn_rcpf(su);
                Pst[wave][quad * 4 + r][col]      = f2bf1(o0[r] * rl);
                Pst[wave][quad * 4 + r][col + 16] = f2bf1(o1[r] * rl);
            }
            bf16x8 g0f = *(const bf16x8*)(ghb + (size_t)h * 1024 + (size_t)col * 32 + quad * 8);
            bf16x8 g1f = *(const bf16x8*)(ghb + (size_t)h * 1024 + (size_t)(16 + col) * 32 + quad * 8);
            bf16x8 af = *(const bf16x8*)&Pst[wave][col][quad * 8];
            aggr0 = __builtin_amdgcn_mfma_f32_16x16x32_bf16(af, g0f, aggr0, 0, 0, 0);
            aggr1 = __builtin_amdgcn_mfma_f32_16x16x32_bf16(af, g1f, aggr1, 0, 0, 0);
        }

        // ---- epilogue: + b_out + residual, LN2, FFN, residual, scatter store ----
        {
            bf16x8 w1f[2], w2f[2];
#pragma unroll
            for (int ct = 0; ct < 2; ct++) {
                w1f[ct] = *(const bf16x8*)(ff1b + (ct * 16 + col) * 32 + quad * 8);
                w2f[ct] = *(const bf16x8*)(ff2b + (ct * 16 + col) * 32 + quad * 8);
            }
            float bo0 = b_out[col], bo1 = b_out[col + 16];
            float g20 = g2[col], g21 = g2[col + 16], be20 = be2[col], be21 = be2[col + 16];
            float fb10 = ffb1[col], fb11 = ffb1[col + 16];
            float fb20 = ffb2[col], fb21 = ffb2[col + 16];

            f32x4 a0 = aggr0, a1 = aggr1;
            int trow[4];
#pragma unroll
            for (int r = 0; r < 4; r++) trow[r] = (int)order[b * 256 + srow + quad * 4 + r];

#pragma unroll
            for (int r = 0; r < 4; r++) {
                a0[r] += x[(size_t)trow[r] * 32 + col] + bo0;
                a1[r] += x[(size_t)trow[r] * 32 + 16 + col] + bo1;
            }

            f32x4 xn0, xn1;
#pragma unroll
            for (int r = 0; r < 4; r++) {
                float s = a0[r] + a1[r];
                s += __shfl_xor(s, 1); s += __shfl_xor(s, 2); s += __shfl_xor(s, 4); s += __shfl_xor(s, 8);
                float mu = s * (1.0f / 32.0f);
                float c0 = a0[r] - mu, c1 = a1[r] - mu;
                float v = c0 * c0 + c1 * c1;
                v += __shfl_xor(v, 1); v += __shfl_xor(v, 2); v += __shfl_xor(v, 4); v += __shfl_xor(v, 8);
                float rstd = rsqrtf(v * (1.0f / 32.0f) + 1e-5f);
                xn0[r] = c0 * rstd * g20 + be20;
                xn1[r] = c1 * rstd * g21 + be21;
            }

#pragma unroll
            for (int r = 0; r < 4; r++) {
                Pst[wave][quad * 4 + r][col]      = f2bf1(xn0[r]);
                Pst[wave][quad * 4 + r][col + 16] = f2bf1(xn1[r]);
            }
            bf16x8 af1 = *(const bf16x8*)&Pst[wave][col][quad * 8];
            f32x4 z = { 0.f, 0.f, 0.f, 0.f };
            f32x4 h0 = __builtin_amdgcn_mfma_f32_16x16x32_bf16(af1, w1f[0], z, 0, 0, 0);
            f32x4 h1 = __builtin_amdgcn_mfma_f32_16x16x32_bf16(af1, w1f[1], z, 0, 0, 0);
#pragma unroll
            for (int r = 0; r < 4; r++) {
                h0[r] = fmaxf(h0[r] + fb10, 0.f);
                h1[r] = fmaxf(h1[r] + fb11, 0.f);
            }

#pragma unroll
            for (int r = 0; r < 4; r++) {
                Pst[wave][quad * 4 + r][col]      = f2bf1(h0[r]);
                Pst[wave][quad * 4 + r][col + 16] = f2bf1(h1[r]);
            }
            bf16x8 af2 = *(const bf16x8*)&Pst[wave][col][quad * 8];
            f32x4 f0 = __builtin_amdgcn_mfma_f32_16x16x32_bf16(af2, w2f[0], z, 0, 0, 0);
            f32x4 f1 = __builtin_amdgcn_mfma_f32_16x16x32_bf16(af2, w2f[1], z, 0, 0, 0);

#pragma unroll
            for (int r = 0; r < 4; r++) {
                out[(size_t)trow[r] * 32 + col]      = a0[r] + f0[r] + fb20;
                out[(size_t)trow[r] * 32 + 16 + col] = a1[r] + f1[r] + fb21;
            }
        }
    }
}

extern "C" void kernel_launch(void* const* d_in, const int* in_sizes, int n_in,
                              void* d_out, int out_size, void* d_ws, size_t ws_size,
                              hipStream_t stream) {
    (void)in_sizes; (void)n_in; (void)out_size; (void)ws_size;
    const float* x      = (const float*)d_in[0];
    const float* coords = (const float*)d_in[1];
    const float* wq     = (const float*)d_in[2];
    const float* wk     = (const float*)d_in[3];
    const float* wv     = (const float*)d_in[4];
    const float* w_rpe  = (const float*)d_in[5];
    const float* w_out  = (const float*)d_in[6];
    const float* b_out  = (const float*)d_in[7];
    const float* g1     = (const float*)d_in[8];
    const float* be1    = (const float*)d_in[9];
    const float* g2     = (const float*)d_in[10];
    const float* be2    = (const float*)d_in[11];
    const float* ffw1   = (const float*)d_in[12];
    const float* ffb1   = (const float*)d_in[13];
    const float* ffw2   = (const float*)d_in[14];
    const float* ffb2   = (const float*)d_in[15];
    float* out = (float*)d_out;

    char* ws = (char*)d_ws;
    unsigned int* hseg    = (unsigned int*)(ws);                     // 256 KB
    unsigned int* locmemb = (unsigned int*)(ws + 512 * 1024);        // 256 KB
    unsigned int* keyarr  = (unsigned int*)(ws + 768 * 1024);        // 256 KB
    unsigned int* order   = (unsigned int*)(ws + 1024 * 1024);       // 256 KB
    float*        w2      = (float*)(ws + 1280 * 1024);              // 16 f32
    unsigned short* ff1b  = (unsigned short*)(ws + 1536 * 1024);     // 1024 u16
    unsigned short* ff2b  = ff1b + 1024;                             // 1024 u16
    unsigned short* mhb   = ff2b + 1024;                             // 8192 u16
    unsigned short* ghb   = mhb + 8192;                              // 8192 u16

    kprep  <<<256, 256, 0, stream>>>(coords, wq, wk, wv, w_out, ffw1, ffw2, w_rpe,
                                     hseg, locmemb, keyarr,
                                     ff1b, ff2b, mhb, ghb, w2);
    kbucket<<<256, 512, 0, stream>>>(hseg, locmemb, keyarr, order);
    kattn  <<<512, 256, 0, stream>>>(x, g1, be1, order, coords, w2, mhb, ghb,
                                     b_out, g2, be2,
                                     ff1b, ffb1, ff2b, ffb2, out);
}

// Round 18
// 161.487 us; speedup vs baseline: 1.0440x; 1.0440x over previous
//
#include <hip/hip_runtime.h>
#include <hip/hip_bf16.h>

#define DEV __device__ __forceinline__

typedef __attribute__((ext_vector_type(8))) short bf16x8;
typedef __attribute__((ext_vector_type(4))) float f32x4;

// N=65536 tokens, 8 heads, head dim 32, feature dim 256, block 256
static constexpr float QSCALE = 0.17677669529663687f; // 1/sqrt(32)
static constexpr float LOG2E  = 1.4426950408889634f;

DEV unsigned short f2bf(float f) {
    union { float f; unsigned int u; } a; a.f = f;
    unsigned int r = (a.u + 0x7fffu + ((a.u >> 16) & 1u)) >> 16; // RNE
    return (unsigned short)r;
}
DEV unsigned int pack2bf(float lo, float hi) {   // v_cvt_pk_bf16_f32 on gfx950
    float2 t; t.x = lo; t.y = hi;
    __hip_bfloat162 h = __float22bfloat162_rn(t);
    unsigned int u; __builtin_memcpy(&u, &h, 4);
    return u;
}
DEV unsigned short f2bf1(float f) {              // 1 VALU (cvt_pk, keep low half)
    return (unsigned short)(pack2bf(f, 0.f) & 0xffffu);
}

// ---------------- pre-chain, 2 dispatches ----------------
// K1: block-local counting sort + keyarr + small-weight prep + per-head fused
// matrices M_h = s*wq_h^T@wk_h and G_h[f][o] = sum_d wv[h32+d][f]*wout[o][h32+d].
__global__ __launch_bounds__(256) void kprep(
    const float* __restrict__ coords,
    const float* __restrict__ wq, const float* __restrict__ wk,
    const float* __restrict__ wv, const float* __restrict__ w_out,
    const float* __restrict__ ff1, const float* __restrict__ ff2,
    const float* __restrict__ w_rpe,
    unsigned int* __restrict__ hseg,        // [256 kblocks][256 buckets] packed
    unsigned int* __restrict__ locmemb,     // [256 kblocks][256] bucket-grouped ids
    unsigned int* __restrict__ keyarr,      // [65536] float bits of coords[:,0]
    unsigned short* ff1b, unsigned short* ff2b,
    unsigned short* mhb, unsigned short* ghb, float* w2)
{
    __shared__ unsigned int lhist[256];
    __shared__ unsigned int s[256];
    __shared__ unsigned int loff[256];
    __shared__ float part[4];
    int tid = threadIdx.x;
    int g = blockIdx.x * 256 + tid;

    lhist[tid] = 0u;
    float v = coords[(size_t)g * 3];
    keyarr[g] = __float_as_uint(v);          // keys >= 0 -> bit compare works
    int b8 = (int)(v * 256.0f);
    b8 = b8 < 0 ? 0 : (b8 > 255 ? 255 : b8);
    __syncthreads();
    unsigned int myl = atomicAdd(&lhist[b8], 1u);

    // FFN weight conversion (blocks 0..7)
    if (g < 1024)            ff1b[g] = f2bf(ff1[g]);
    else if (g < 2048)       ff2b[g - 1024] = f2bf(ff2[g - 1024]);

    // fused per-head matrices (blocks 64..79): p = (h<<1)|m
    if (blockIdx.x >= 64 && blockIdx.x < 80) {
        int pp = blockIdx.x - 64;
        int m = pp & 1, h = pp >> 1;
#pragma unroll 1
        for (int k = 0; k < 4; k++) {
            int e = k * 256 + tid;
            int gg = e >> 5, f = e & 31;     // gg = output col (g of T / o), f = k-dim
            float acc = 0.f;
            if (m == 0) {
#pragma unroll 4
                for (int d = 0; d < 32; d++)
                    acc += wq[(h * 32 + d) * 32 + f] * wk[(h * 32 + d) * 32 + gg];
                mhb[h * 1024 + gg * 32 + f] = f2bf(acc * (QSCALE * LOG2E));
            } else {
#pragma unroll 4
                for (int d = 0; d < 32; d++)
                    acc += wv[(h * 32 + d) * 32 + f] * w_out[gg * 256 + h * 32 + d];
                ghb[h * 1024 + gg * 32 + f] = f2bf(acc);
            }
        }
    }

    if (blockIdx.x >= 240) {                 // 16 blocks: w2[p], p = h*2 + c
        int p = blockIdx.x - 240;
        int h = p >> 1, c = p & 1;
        int d = tid >> 3, j = tid & 7;
        float w = w_rpe[(h * 32 + d) * 16 + c * 8 + j];
        float w2v = w * w;
        for (int m = 32; m >= 1; m >>= 1) w2v += __shfl_xor(w2v, m);
        if ((tid & 63) == 0) part[tid >> 6] = w2v;
        __syncthreads();
        if (tid == 0) w2[p] = (part[0] + part[1] + part[2] + part[3]) * (1.0f / 256.0f) * LOG2E;
    }
    __syncthreads();

    unsigned int cnt = lhist[tid];
    s[tid] = cnt; __syncthreads();
    for (int off = 1; off < 256; off <<= 1) {
        unsigned int t = (tid >= off) ? s[tid - off] : 0u;
        __syncthreads();
        s[tid] += t;
        __syncthreads();
    }
    unsigned int lexcl = s[tid] - cnt;
    loff[tid] = lexcl;
    hseg[blockIdx.x * 256 + tid] = (lexcl << 16) | cnt;   // coalesced, packed
    __syncthreads();

    locmemb[blockIdx.x * 256 + loff[b8] + myl] = (unsigned int)g;
}

// K2: one block per bucket, 512 threads (unchanged)
__global__ __launch_bounds__(512) void kbucket(
    const unsigned int* __restrict__ hseg,
    const unsigned int* __restrict__ locmemb,
    const unsigned int* __restrict__ keyarr,
    unsigned int* __restrict__ order)
{
    __shared__ unsigned int s[256];
    __shared__ unsigned int csum[512];
    __shared__ unsigned int mkey[512];
    __shared__ unsigned int midx[512];
    int tid = threadIdx.x;
    int b = blockIdx.x;
    int t8 = tid & 255, hi = tid >> 8;

    unsigned int tot = 0;
#pragma unroll 16
    for (int k = 0; k < 128; k++) tot += hseg[(hi * 128 + k) * 256 + t8] & 0xffffu;
    csum[tid] = tot;
    __syncthreads();
    if (tid < 256) s[tid] = csum[tid] + csum[tid + 256];
    __syncthreads();

    for (int off = 1; off < 256; off <<= 1) {
        unsigned int t = 0;
        if (tid < 256 && tid >= off) t = s[tid - off];
        __syncthreads();
        if (tid < 256) s[tid] += t;
        __syncthreads();
    }
    unsigned int start = (b == 0) ? 0u : s[b - 1];
    __syncthreads();

    unsigned int segcnt = 0, segoff = 0;
    if (tid < 256) {
        unsigned int pk = hseg[tid * 256 + b];
        segcnt = pk & 0xffffu;
        segoff = pk >> 16;
    }
    __syncthreads();
    if (tid < 256) s[tid] = segcnt;
    __syncthreads();
    for (int off = 1; off < 256; off <<= 1) {
        unsigned int t = 0;
        if (tid < 256 && tid >= off) t = s[tid - off];
        __syncthreads();
        if (tid < 256) s[tid] += t;
        __syncthreads();
    }
    unsigned int dst = (tid < 256) ? s[tid] - segcnt : 0u;
    unsigned int cntb = s[255];
    if (cntb > 512u) cntb = 512u;
    __syncthreads();

    if (tid < 256) {
        for (unsigned int j = 0; j < segcnt; j++) {
            unsigned int p = dst + j;
            if (p < 512u) midx[p] = locmemb[tid * 256 + segoff + j];
        }
    }
    __syncthreads();
    for (unsigned int p = tid; p < cntb; p += 512) mkey[p] = keyarr[midx[p]];
    __syncthreads();

    for (unsigned int m = tid; m < cntb; m += 512) {
        unsigned int km = mkey[m], im = midx[m];
        unsigned int r = 0;
        for (unsigned int j = 0; j < cntb; j++) {
            unsigned int kj = mkey[j];
            r += (kj < km || (kj == km && midx[j] < im)) ? 1u : 0u;
        }
        order[start + r] = im;
    }
}

// ---------------- fused attention, Q/K/V-free (R15 exact -- measured best) ---------
// R18: REVERT to R15 (best measured: kattn 56.9 us, total 162.2, VGPR 76,
// FETCH 6.8 MB). R17's uniform dual-quarter (grid 512) measured -4%: the
// 2-blocks/CU (8-wave) penalty (Q8 ~ 1.35x Q12, not the predicted 1.2x)
// outweighed the tail fix, and R15's tail was partially absorbed by inter-CU
// drift anyway. Final configuration:
//  - grid 768 = 512 single-quarter + 256 dual-quarter (tail-fill) blocks
//  - Q/K/V-free algebra: per-head 32x32 fused M_h (score) / G_h (out-proj)
//  - half-split S computation (32-VGPR acc live range; no spill)
//  - per-head sched_barrier(0) anchor (waves drift at runtime)
// LDS: xn 16384 + xnT 16896 + kext 2048 + pf 2048 + Pst 9216 = 46592 -> 3/CU.
__global__ __launch_bounds__(256, 3) void kattn(
    const float* __restrict__ x, const float* __restrict__ g1, const float* __restrict__ be1,
    const unsigned int* __restrict__ order, const float* __restrict__ coords,
    const float* __restrict__ w2,
    const unsigned short* __restrict__ mhb, const unsigned short* __restrict__ ghb,
    const float* __restrict__ b_out,
    const float* __restrict__ g2, const float* __restrict__ be2,
    const unsigned short* __restrict__ ff1b, const float* __restrict__ ffb1,
    const unsigned short* __restrict__ ff2b, const float* __restrict__ ffb2,
    float* __restrict__ out)
{
    __shared__ unsigned short xn[256][32];       // 16384 B  LN'd x, chunk-swizzled
    __shared__ unsigned short xnT[32][264];      // 16896 B  [feature][jinv(token)]
    __shared__ unsigned short kext[256][4];      //  2048 B  {a, b, a^2, b^2} bf16
    __shared__ float2 pf[256];                   //  2048 B  f32 coords
    __shared__ unsigned short Pst[4][16][72];    //  9216 B  wave-private staging

    int bh = blockIdx.x;
    int p = bh & 255;
    int b = (p & 7) * 32 + (p >> 3);            // bucket; quarters share bh&7 (XCD)
    int q0 = bh >> 8;                           // first quarter (0,1,2)
    int nq = (bh < 256) ? 2 : 1;                // blocks 0..255 also do quarter 3
    int tid = threadIdx.x, wave = tid >> 6, lane = tid & 63;
    int col = lane & 15, quad = lane >> 4;

    // ---- stage A: gather x row, LN1 -> xn (swizzled) + xnT (permuted transpose) ----
    {
        int t = tid;
        int tok = (int)order[b * 256 + t];
        float a = coords[tok * 3 + 1], bb = coords[tok * 3 + 2];
        pf[t] = make_float2(a, bb);
        uint2 kv;
        kv.x = pack2bf(a, bb);
        kv.y = pack2bf(a * a, bb * bb);
        *(uint2*)&kext[t][0] = kv;

        float xv[32];
        const float4* xr = (const float4*)(x + (size_t)tok * 32);
#pragma unroll
        for (int q4 = 0; q4 < 8; q4++) {
            float4 v4 = xr[q4];
            xv[q4 * 4 + 0] = v4.x; xv[q4 * 4 + 1] = v4.y; xv[q4 * 4 + 2] = v4.z; xv[q4 * 4 + 3] = v4.w;
        }
        float mu = 0.f;
#pragma unroll
        for (int d = 0; d < 32; d++) mu += xv[d];
        mu *= (1.0f / 32.0f);
        float var = 0.f;
#pragma unroll
        for (int d = 0; d < 32; d++) { float c = xv[d] - mu; var += c * c; }
        var *= (1.0f / 32.0f);
        float rstd = rsqrtf(var + 1e-5f);
        unsigned int pk[16];
#pragma unroll
        for (int w = 0; w < 16; w++) {
            float a2 = (xv[2 * w] - mu) * rstd * g1[2 * w] + be1[2 * w];
            float b2 = (xv[2 * w + 1] - mu) * rstd * g1[2 * w + 1] + be1[2 * w + 1];
            pk[w] = pack2bf(a2, b2);
        }
        int v = (t >> 1) & 3;                    // chunk swizzle key
        uint4* dst = (uint4*)&xn[t][0];
#pragma unroll
        for (int w4 = 0; w4 < 4; w4++) {
            uint4 v4; v4.x = pk[w4*4]; v4.y = pk[w4*4+1]; v4.z = pk[w4*4+2]; v4.w = pk[w4*4+3];
            dst[w4 ^ v] = v4;                    // logical chunk w4 -> physical w4^v
        }
        int jv = (t & ~63) + (t & 15) * 4 + ((t >> 4) & 3);   // jinv permutation
#pragma unroll
        for (int f = 0; f < 16; f++) {
            xnT[2 * f][jv]     = (unsigned short)(pk[f] & 0xffffu);
            xnT[2 * f + 1][jv] = (unsigned short)(pk[f] >> 16);
        }
    }
    __syncthreads();                             // stage A visibility (required)

    int kswz = (quad ^ ((col >> 1) & 3)) * 8;    // B-read swizzle (row = nt*16+col)
    const f32x4 zz = { 0.f, 0.f, 0.f, 0.f };

#pragma unroll 1
    for (int qi = 0; qi < nq; qi++) {
        int qbase = (qi == 0 ? q0 : 3) * 64;     // query window base
        // per-quarter hoists
        int srow = qbase + wave * 16;            // strip base (16 q-rows per wave)
        int myrow = srow + col;                  // A-row of this lane
        bf16x8 qa_x = *(const bf16x8*)&xn[myrow][(quad ^ ((myrow >> 1) & 3)) * 8];
        float2 pm = pf[myrow];

        f32x4 aggr0 = { 0.f, 0.f, 0.f, 0.f }, aggr1 = { 0.f, 0.f, 0.f, 0.f };

#pragma unroll 1
        for (int h = 0; h < 8; h++) {
            __builtin_amdgcn_sched_barrier(0);   // compile-time anchor only; waves drift

            // per-head score matrix fragments (global 16 B loads, L2-resident)
            bf16x8 m0 = *(const bf16x8*)(mhb + (size_t)h * 1024 + (size_t)col * 32 + quad * 8);
            bf16x8 m1 = *(const bf16x8*)(mhb + (size_t)h * 1024 + (size_t)(16 + col) * 32 + quad * 8);
            float w0 = w2[2 * h], w1 = w2[2 * h + 1];   // already * log2e
            unsigned int qp0 = quad == 0 ? pack2bf(2.0f * w0 * pm.x, 2.0f * w1 * pm.y) : 0u;
            unsigned int qp1 = quad == 0 ? pack2bf(-w0, -w1) : 0u;
            bf16x8 qe;
            qe[0] = (short)(qp0 & 0xffffu); qe[1] = (short)(qp0 >> 16);
            qe[2] = (short)(qp1 & 0xffffu); qe[3] = (short)(qp1 >> 16);
            qe[4] = 0; qe[5] = 0; qe[6] = 0; qe[7] = 0;

            // T = xns @ M_h (C: col=g-col, row=quad*4+r) -> LDS transpose -> A-frag
            f32x4 t0 = __builtin_amdgcn_mfma_f32_16x16x32_bf16(qa_x, m0, zz, 0, 0, 0);
            f32x4 t1 = __builtin_amdgcn_mfma_f32_16x16x32_bf16(qa_x, m1, zz, 0, 0, 0);
#pragma unroll
            for (int r = 0; r < 4; r++) {
                int ii = quad * 4 + r, sw = (ii >> 1) & 3;
                int ga = col, gb = 16 + col;
                Pst[wave][ii][((ga >> 3) ^ sw) * 8 + (ga & 7)] = f2bf1(t0[r]);
                Pst[wave][ii][((gb >> 3) ^ sw) * 8 + (gb & 7)] = f2bf1(t1[r]);
            }
            bf16x8 ta = *(const bf16x8*)&Pst[wave][col][(quad ^ ((col >> 1) & 3)) * 8];

            // S = T @ xn^T + bias, processed in TWO halves of 8 key-tiles so the
            // accumulator live range peaks at 32 VGPRs (R8's 64 spilled to scratch).
            float rsum[4] = { 0.f, 0.f, 0.f, 0.f };
            f32x4 o0 = zz, o1 = zz;
#pragma unroll 1
            for (int half = 0; half < 2; half++) {
                f32x4 acc8[8];
#pragma unroll
                for (int nt8 = 0; nt8 < 8; nt8++) {
                    int nt = half * 8 + nt8;
                    bf16x8 kb = *(const bf16x8*)&xn[nt * 16 + col][kswz];
                    uint2 kv = *(const uint2*)&kext[nt * 16 + col][0];
                    unsigned int ea0 = quad == 0 ? kv.x : 0u;
                    unsigned int ea1 = quad == 0 ? kv.y : 0u;
                    bf16x8 ke;
                    ke[0] = (short)(ea0 & 0xffffu); ke[1] = (short)(ea0 >> 16);
                    ke[2] = (short)(ea1 & 0xffffu); ke[3] = (short)(ea1 >> 16);
                    ke[4] = 0; ke[5] = 0; ke[6] = 0; ke[7] = 0;
                    f32x4 z = __builtin_amdgcn_mfma_f32_16x16x32_bf16(ta, kb, zz, 0, 0, 0);
                    acc8[nt8] = __builtin_amdgcn_mfma_f32_16x16x32_bf16(qe, ke, z, 0, 0, 0);
                }
#pragma unroll
                for (int cc = 0; cc < 2; cc++) {
                    int c = half * 2 + cc;
#pragma unroll
                    for (int r = 0; r < 4; r++) {
                        float e0 = __builtin_amdgcn_exp2f(acc8[cc * 4 + 0][r]);
                        float e1 = __builtin_amdgcn_exp2f(acc8[cc * 4 + 1][r]);
                        float e2 = __builtin_amdgcn_exp2f(acc8[cc * 4 + 2][r]);
                        float e3 = __builtin_amdgcn_exp2f(acc8[cc * 4 + 3][r]);
                        rsum[r] += (e0 + e1) + (e2 + e3);
                        uint2 pk;
                        pk.x = pack2bf(e0, e1);
                        pk.y = pack2bf(e2, e3);
                        *(uint2*)&Pst[wave][quad * 4 + r][col * 4] = pk;  // kloc = col*4+t
                    }
#pragma unroll
                    for (int k2 = 0; k2 < 2; k2++) {
                        bf16x8 pa = *(const bf16x8*)&Pst[wave][col][k2 * 32 + quad * 8];
                        bf16x8 b0 = *(const bf16x8*)&xnT[col][c * 64 + k2 * 32 + quad * 8];
                        bf16x8 b1 = *(const bf16x8*)&xnT[16 + col][c * 64 + k2 * 32 + quad * 8];
                        o0 = __builtin_amdgcn_mfma_f32_16x16x32_bf16(pa, b0, o0, 0, 0, 0);
                        o1 = __builtin_amdgcn_mfma_f32_16x16x32_bf16(pa, b1, o1, 0, 0, 0);
                    }
                }
            }

            // scale by 1/sum, stage PXs, fused out-proj accumulate via G_h (loaded late)
#pragma unroll
            for (int r = 0; r < 4; r++) {
                float su = rsum[r];
                su += __shfl_xor(su, 1); su += __shfl_xor(su, 2);
                su += __shfl_xor(su, 4); su += __shfl_xor(su, 8);
                float rl = __builtin_amdgcn_rcpf(su);
                Pst[wave][quad * 4 + r][col]      = f2bf1(o0[r] * rl);
                Pst[wave][quad * 4 + r][col + 16] = f2bf1(o1[r] * rl);
            }
            bf16x8 g0f = *(const bf16x8*)(ghb + (size_t)h * 1024 + (size_t)col * 32 + quad * 8);
            bf16x8 g1f = *(const bf16x8*)(ghb + (size_t)h * 1024 + (size_t)(16 + col) * 32 + quad * 8);
            bf16x8 af = *(const bf16x8*)&Pst[wave][col][quad * 8];
            aggr0 = __builtin_amdgcn_mfma_f32_16x16x32_bf16(af, g0f, aggr0, 0, 0, 0);
            aggr1 = __builtin_amdgcn_mfma_f32_16x16x32_bf16(af, g1f, aggr1, 0, 0, 0);
        }

        // ---- epilogue: + b_out + residual, LN2, FFN, residual, scatter store ----
        {
            bf16x8 w1f[2], w2f[2];
#pragma unroll
            for (int ct = 0; ct < 2; ct++) {
                w1f[ct] = *(const bf16x8*)(ff1b + (ct * 16 + col) * 32 + quad * 8);
                w2f[ct] = *(const bf16x8*)(ff2b + (ct * 16 + col) * 32 + quad * 8);
            }
            float bo0 = b_out[col], bo1 = b_out[col + 16];
            float g20 = g2[col], g21 = g2[col + 16], be20 = be2[col], be21 = be2[col + 16];
            float fb10 = ffb1[col], fb11 = ffb1[col + 16];
            float fb20 = ffb2[col], fb21 = ffb2[col + 16];

            f32x4 a0 = aggr0, a1 = aggr1;
            int trow[4];
#pragma unroll
            for (int r = 0; r < 4; r++) trow[r] = (int)order[b * 256 + srow + quad * 4 + r];

#pragma unroll
            for (int r = 0; r < 4; r++) {
                a0[r] += x[(size_t)trow[r] * 32 + col] + bo0;
                a1[r] += x[(size_t)trow[r] * 32 + 16 + col] + bo1;
            }

            f32x4 xn0, xn1;
#pragma unroll
            for (int r = 0; r < 4; r++) {
                float s = a0[r] + a1[r];
                s += __shfl_xor(s, 1); s += __shfl_xor(s, 2); s += __shfl_xor(s, 4); s += __shfl_xor(s, 8);
                float mu = s * (1.0f / 32.0f);
                float c0 = a0[r] - mu, c1 = a1[r] - mu;
                float v = c0 * c0 + c1 * c1;
                v += __shfl_xor(v, 1); v += __shfl_xor(v, 2); v += __shfl_xor(v, 4); v += __shfl_xor(v, 8);
                float rstd = rsqrtf(v * (1.0f / 32.0f) + 1e-5f);
                xn0[r] = c0 * rstd * g20 + be20;
                xn1[r] = c1 * rstd * g21 + be21;
            }

#pragma unroll
            for (int r = 0; r < 4; r++) {
                Pst[wave][quad * 4 + r][col]      = f2bf1(xn0[r]);
                Pst[wave][quad * 4 + r][col + 16] = f2bf1(xn1[r]);
            }
            bf16x8 af1 = *(const bf16x8*)&Pst[wave][col][quad * 8];
            f32x4 z = { 0.f, 0.f, 0.f, 0.f };
            f32x4 h0 = __builtin_amdgcn_mfma_f32_16x16x32_bf16(af1, w1f[0], z, 0, 0, 0);
            f32x4 h1 = __builtin_amdgcn_mfma_f32_16x16x32_bf16(af1, w1f[1], z, 0, 0, 0);
#pragma unroll
            for (int r = 0; r < 4; r++) {
                h0[r] = fmaxf(h0[r] + fb10, 0.f);
                h1[r] = fmaxf(h1[r] + fb11, 0.f);
            }

#pragma unroll
            for (int r = 0; r < 4; r++) {
                Pst[wave][quad * 4 + r][col]      = f2bf1(h0[r]);
                Pst[wave][quad * 4 + r][col + 16] = f2bf1(h1[r]);
            }
            bf16x8 af2 = *(const bf16x8*)&Pst[wave][col][quad * 8];
            f32x4 f0 = __builtin_amdgcn_mfma_f32_16x16x32_bf16(af2, w2f[0], z, 0, 0, 0);
            f32x4 f1 = __builtin_amdgcn_mfma_f32_16x16x32_bf16(af2, w2f[1], z, 0, 0, 0);

#pragma unroll
            for (int r = 0; r < 4; r++) {
                out[(size_t)trow[r] * 32 + col]      = a0[r] + f0[r] + fb20;
                out[(size_t)trow[r] * 32 + 16 + col] = a1[r] + f1[r] + fb21;
            }
        }
    }
}

extern "C" void kernel_launch(void* const* d_in, const int* in_sizes, int n_in,
                              void* d_out, int out_size, void* d_ws, size_t ws_size,
                              hipStream_t stream) {
    (void)in_sizes; (void)n_in; (void)out_size; (void)ws_size;
    const float* x      = (const float*)d_in[0];
    const float* coords = (const float*)d_in[1];
    const float* wq     = (const float*)d_in[2];
    const float* wk     = (const float*)d_in[3];
    const float* wv     = (const float*)d_in[4];
    const float* w_rpe  = (const float*)d_in[5];
    const float* w_out  = (const float*)d_in[6];
    const float* b_out  = (const float*)d_in[7];
    const float* g1     = (const float*)d_in[8];
    const float* be1    = (const float*)d_in[9];
    const float* g2     = (const float*)d_in[10];
    const float* be2    = (const float*)d_in[11];
    const float* ffw1   = (const float*)d_in[12];
    const float* ffb1   = (const float*)d_in[13];
    const float* ffw2   = (const float*)d_in[14];
    const float* ffb2   = (const float*)d_in[15];
    float* out = (float*)d_out;

    char* ws = (char*)d_ws;
    unsigned int* hseg    = (unsigned int*)(ws);                     // 256 KB
    unsigned int* locmemb = (unsigned int*)(ws + 512 * 1024);        // 256 KB
    unsigned int* keyarr  = (unsigned int*)(ws + 768 * 1024);        // 256 KB
    unsigned int* order   = (unsigned int*)(ws + 1024 * 1024);       // 256 KB
    float*        w2      = (float*)(ws + 1280 * 1024);              // 16 f32
    unsigned short* ff1b  = (unsigned short*)(ws + 1536 * 1024);     // 1024 u16
    unsigned short* ff2b  = ff1b + 1024;                             // 1024 u16
    unsigned short* mhb   = ff2b + 1024;                             // 8192 u16
    unsigned short* ghb   = mhb + 8192;                              // 8192 u16

    kprep  <<<256, 256, 0, stream>>>(coords, wq, wk, wv, w_out, ffw1, ffw2, w_rpe,
                                     hseg, locmemb, keyarr,
                                     ff1b, ff2b, mhb, ghb, w2);
    kbucket<<<256, 512, 0, stream>>>(hseg, locmemb, keyarr, order);
    kattn  <<<768, 256, 0, stream>>>(x, g1, be1, order, coords, w2, mhb, ghb,
                                     b_out, g2, be2,
                                     ff1b, ffb1, ff2b, ffb2, out);
}